// Round 21
// baseline (626.620 us; speedup 1.0000x reference)
//
#include <hip/hip_runtime.h>
#include <hip/hip_bf16.h>
#include <math.h>

#define TT   2048
#define CC   2048
#define NB   2
#define NH   16
#define NKV  4
#define HDIM 128
#define NFFN 5632

typedef __attribute__((ext_vector_type(8))) short     bf8;
typedef __attribute__((ext_vector_type(4))) float     f32x4;
typedef __attribute__((ext_vector_type(8))) unsigned short u16x8;
typedef __attribute__((ext_vector_type(4))) unsigned short u16x4;

__device__ __forceinline__ float b2f(unsigned short u) {
    union { unsigned u; float f; } v; v.u = ((unsigned)u) << 16; return v.f;
}
__device__ __forceinline__ unsigned short f2bf(float f) {
    union { float f; unsigned u; } v; v.f = f;
    unsigned r = (v.u + 0x7fffu + ((v.u >> 16) & 1u)) >> 16;
    return (unsigned short)r;
}
__device__ __forceinline__ void gll16(const void* g, void* l) {
    __builtin_amdgcn_global_load_lds((const __attribute__((address_space(1))) void*)g,
                                     (__attribute__((address_space(3))) void*)l, 16, 0, 0);
}

// ============================ f32 -> bf16 convert ============================
__global__ __launch_bounds__(256) void cvt_k(const float* __restrict__ in,
        __hip_bfloat16* __restrict__ out)
{
    const size_t i = ((size_t)blockIdx.x * 256 + threadIdx.x) * 8;
    float4 a = *(const float4*)(in + i);
    float4 b = *(const float4*)(in + i + 4);
    u16x8 v;
    v[0] = f2bf(a.x); v[1] = f2bf(a.y); v[2] = f2bf(a.z); v[3] = f2bf(a.w);
    v[4] = f2bf(b.x); v[5] = f2bf(b.y); v[6] = f2bf(b.z); v[7] = f2bf(b.w);
    *(u16x8*)((unsigned short*)out + i) = v;
}

// merged qkv-weight convert
__global__ __launch_bounds__(256) void cvt3_k(const float* __restrict__ wq,
        const float* __restrict__ wk, const float* __restrict__ wv,
        __hip_bfloat16* __restrict__ out)
{
    const int row = blockIdx.x;
    const float* src = (row < 2048) ? (wq + (size_t)row * CC)
                     : (row < 2560) ? (wk + (size_t)(row - 2048) * CC)
                                    : (wv + (size_t)(row - 2560) * CC);
    const int e0 = threadIdx.x * 8;
    float4 a = *(const float4*)(src + e0);
    float4 b = *(const float4*)(src + e0 + 4);
    u16x8 v;
    v[0] = f2bf(a.x); v[1] = f2bf(a.y); v[2] = f2bf(a.z); v[3] = f2bf(a.w);
    v[4] = f2bf(b.x); v[5] = f2bf(b.y); v[6] = f2bf(b.z); v[7] = f2bf(b.w);
    *(u16x8*)((unsigned short*)out + (size_t)row * CC + e0) = v;
}

// merged w1/w2 convert
__global__ __launch_bounds__(256) void cvt2_k(const float* __restrict__ w1,
        const float* __restrict__ w2,
        __hip_bfloat16* __restrict__ o1, __hip_bfloat16* __restrict__ o2)
{
    const int row = blockIdx.x;
    const float* src;
    unsigned short* dst;
    if (row < NFFN) { src = w1 + (size_t)row * CC; dst = (unsigned short*)o1 + (size_t)row * CC; }
    else            { src = w2 + (size_t)(row - NFFN) * CC; dst = (unsigned short*)o2 + (size_t)(row - NFFN) * CC; }
    const int e0 = threadIdx.x * 8;
    float4 a = *(const float4*)(src + e0);
    float4 b = *(const float4*)(src + e0 + 4);
    u16x8 v;
    v[0] = f2bf(a.x); v[1] = f2bf(a.y); v[2] = f2bf(a.z); v[3] = f2bf(a.w);
    v[4] = f2bf(b.x); v[5] = f2bf(b.y); v[6] = f2bf(b.z); v[7] = f2bf(b.w);
    *(u16x8*)(dst + e0) = v;
}

// ============================ RMSNorm ============================
__global__ __launch_bounds__(256) void rms_f32_k(const float* __restrict__ x,
        const float* __restrict__ g, __hip_bfloat16* __restrict__ o)
{
    const size_t row = blockIdx.x;
    const int e0 = threadIdx.x * 8;
    float4 a = *(const float4*)(x + row * CC + e0);
    float4 b = *(const float4*)(x + row * CC + e0 + 4);
    float vals[8] = {a.x, a.y, a.z, a.w, b.x, b.y, b.z, b.w};
    float s = 0.f;
    #pragma unroll
    for (int e = 0; e < 8; ++e) s += vals[e] * vals[e];
    #pragma unroll
    for (int off = 32; off; off >>= 1) s += __shfl_xor(s, off);
    __shared__ float wsum[4];
    if ((threadIdx.x & 63) == 0) wsum[threadIdx.x >> 6] = s;
    __syncthreads();
    float scale = rsqrtf((wsum[0] + wsum[1] + wsum[2] + wsum[3]) * (1.0f / CC) + 1e-5f);
    float4 g0 = *(const float4*)(g + e0);
    float4 g1 = *(const float4*)(g + e0 + 4);
    float gs[8] = {g0.x, g0.y, g0.z, g0.w, g1.x, g1.y, g1.z, g1.w};
    u16x8 ov;
    #pragma unroll
    for (int e = 0; e < 8; ++e) ov[e] = f2bf(vals[e] * scale * gs[e]);
    *(u16x8*)((unsigned short*)o + row * CC + e0) = ov;
}

__global__ __launch_bounds__(256) void rms_bf16_k(const __hip_bfloat16* __restrict__ x,
        const float* __restrict__ g, __hip_bfloat16* __restrict__ o)
{
    const size_t row = blockIdx.x;
    const int e0 = threadIdx.x * 8;
    u16x8 xv = *(const u16x8*)((const unsigned short*)x + row * CC + e0);
    float vals[8];
    #pragma unroll
    for (int e = 0; e < 8; ++e) vals[e] = b2f(xv[e]);
    float s = 0.f;
    #pragma unroll
    for (int e = 0; e < 8; ++e) s += vals[e] * vals[e];
    #pragma unroll
    for (int off = 32; off; off >>= 1) s += __shfl_xor(s, off);
    __shared__ float wsum[4];
    if ((threadIdx.x & 63) == 0) wsum[threadIdx.x >> 6] = s;
    __syncthreads();
    float scale = rsqrtf((wsum[0] + wsum[1] + wsum[2] + wsum[3]) * (1.0f / CC) + 1e-5f);
    float4 g0 = *(const float4*)(g + e0);
    float4 g1 = *(const float4*)(g + e0 + 4);
    float gs[8] = {g0.x, g0.y, g0.z, g0.w, g1.x, g1.y, g1.z, g1.w};
    u16x8 ov;
    #pragma unroll
    for (int e = 0; e < 8; ++e) ov[e] = f2bf(vals[e] * scale * gs[e]);
    *(u16x8*)((unsigned short*)o + row * CC + e0) = ov;
}

// ============================ 128^2 bf16 MFMA GEMM, double-buffered (2ph) ============================
#define GBM 128
#define GBN 128
#define GBK 32

// fused QKV GEMM (N=3072, 2ph) + RoPE epilogue
__global__ __launch_bounds__(256) void gemm_qkv_db(
        const __hip_bfloat16* __restrict__ A,
        const __hip_bfloat16* __restrict__ W,
        const float* __restrict__ fc,
        __hip_bfloat16* __restrict__ qo,
        __hip_bfloat16* __restrict__ ko,
        __hip_bfloat16* __restrict__ vto,
        int M, int K)
{
    __shared__ alignas(16) __hip_bfloat16 As[2][GBM][GBK];
    __shared__ alignas(16) __hip_bfloat16 Ws[2][GBN][GBK];
    const int tid  = threadIdx.x;
    const int lane = tid & 63;
    const int wid  = tid >> 6;
    const int wr = wid >> 1, wc = wid & 1;
    const int nwg = gridDim.x * gridDim.y;
    const int lin = blockIdx.y * gridDim.x + blockIdx.x;
    const int nlin = (lin & 7) * (nwg >> 3) + (lin >> 3);
    const int bxs = nlin % gridDim.x, bys = nlin / gridDim.x;
    const int bm = bys * GBM, bn = bxs * GBN;
    const int l4  = lane >> 2;
    const int lk8 = (lane & 3) * 8;
    const int fr  = lane & 15;
    const int fk  = (lane >> 4) * 8;

    f32x4 acc[4][4];
    #pragma unroll
    for (int m = 0; m < 4; ++m)
        #pragma unroll
        for (int n = 0; n < 4; ++n) acc[m][n] = (f32x4){0.f, 0.f, 0.f, 0.f};

    const __hip_bfloat16* ga0 = A + (size_t)(bm + wid * 32 + l4) * K + lk8;
    const __hip_bfloat16* ga1 = A + (size_t)(bm + wid * 32 + 16 + l4) * K + lk8;
    const __hip_bfloat16* gw0 = W + (size_t)(bn + wid * 32 + l4) * K + lk8;
    const __hip_bfloat16* gw1 = W + (size_t)(bn + wid * 32 + 16 + l4) * K + lk8;

    const int nt = K >> 5;
    gll16(ga0, &As[0][wid * 32][0]);
    gll16(ga1, &As[0][wid * 32 + 16][0]);
    gll16(gw0, &Ws[0][wid * 32][0]);
    gll16(gw1, &Ws[0][wid * 32 + 16][0]);

    #pragma unroll 2
    for (int t = 0; t < nt; ++t) {
        const int cur = t & 1;
        __syncthreads();
        if (t + 1 < nt) {
            const int k1 = (t + 1) << 5;
            const int nx = cur ^ 1;
            gll16(ga0 + k1, &As[nx][wid * 32][0]);
            gll16(ga1 + k1, &As[nx][wid * 32 + 16][0]);
            gll16(gw0 + k1, &Ws[nx][wid * 32][0]);
            gll16(gw1 + k1, &Ws[nx][wid * 32 + 16][0]);
        }
        bf8 af[4];
        #pragma unroll
        for (int m = 0; m < 4; ++m)
            af[m] = *(const bf8*)&As[cur][wr * 64 + m * 16 + fr][fk];
        #pragma unroll
        for (int n = 0; n < 4; ++n) {
            bf8 wf = *(const bf8*)&Ws[cur][wc * 64 + n * 16 + fr][fk];
            #pragma unroll
            for (int m = 0; m < 4; ++m)
                acc[m][n] = __builtin_amdgcn_mfma_f32_16x16x32_bf16(af[m], wf, acc[m][n], 0, 0, 0);
        }
    }

    const int rj = (lane >> 4) * 4;
    #pragma unroll
    for (int m = 0; m < 4; ++m) {
        #pragma unroll
        for (int n = 0; n < 4; ++n) {
            const int col = bn + wc * 64 + n * 16 + fr;
            const int row0 = bm + wr * 64 + m * 16 + rj;
            if (col < 2560) {
                const int i2 = ((col & 127) >> 1) * 2;
                const int role = col & 1;
                #pragma unroll
                for (int j = 0; j < 4; ++j) {
                    const int t0 = (row0 + j) & (TT - 1);
                    const float cv = fc[t0 * HDIM + i2];
                    const float sv = fc[t0 * HDIM + i2 + 1];
                    const float v = acc[m][n][j];
                    const float partner = __shfl_xor(v, 1);
                    const float o = role ? (partner * sv + v * cv) : (v * cv - partner * sv);
                    if (col < 2048)
                        ((unsigned short*)qo)[(size_t)(row0 + j) * CC + col] = f2bf(o);
                    else
                        ((unsigned short*)ko)[(size_t)(row0 + j) * (NKV * HDIM) + (col - 2048)] = f2bf(o);
                }
            } else {
                const int vc = col - 2560;
                const int g = vc >> 7, d = vc & 127;
                const int b = row0 >> 11, t0 = row0 & (TT - 1);
                unsigned short* vp = (unsigned short*)vto +
                    ((size_t)(b * NKV + g) * HDIM + d) * TT + t0;
                u16x4 ov;
                #pragma unroll
                for (int j = 0; j < 4; ++j) ov[j] = f2bf(acc[m][n][j]);
                *(u16x4*)vp = ov;
            }
        }
    }
}

// ============================ 128x256 bf16 MFMA GEMM, 4-phase + counted-vmcnt (T4) ============================
// 3 LDS buffers (144KB), prefetch depth 2; tile-boundary sync = s_waitcnt vmcnt(6) + raw s_barrier
// (never drains the in-flight next-next-tile stage). Epilogue tiles use vmcnt(0).
#define PBM 128
#define PBN 256
#define PBK 64

template<int EPI, int OUTB>
__global__ __launch_bounds__(512) void gemm_8p(
        const __hip_bfloat16* __restrict__ A,
        const __hip_bfloat16* __restrict__ W,
        const void* __restrict__ Rp,
        void* __restrict__ Cp,
        int M, int N, int K)
{
    __shared__ alignas(16) __hip_bfloat16 As[3][PBM][PBK];   // 48KB
    __shared__ alignas(16) __hip_bfloat16 Ws[3][PBN][PBK];   // 96KB
    const int tid  = threadIdx.x;
    const int lane = tid & 63;
    const int wid  = tid >> 6;
    const int wr = wid >> 2, wc = wid & 3;
    const int nwg = gridDim.x * gridDim.y;
    const int lin = blockIdx.y * gridDim.x + blockIdx.x;
    const int nlin = (lin & 7) * (nwg >> 3) + (lin >> 3);
    const int bxs = nlin % gridDim.x, bys = nlin / gridDim.x;
    const int bm = bys * PBM, bn = bxs * PBN;
    const int fr = lane & 15;
    const int hi = lane >> 4;

    f32x4 acc[4][4];
    #pragma unroll
    for (int m = 0; m < 4; ++m)
        #pragma unroll
        for (int n = 0; n < 4; ++n) acc[m][n] = (f32x4){0.f, 0.f, 0.f, 0.f};

    const unsigned short* Ag = (const unsigned short*)A;
    const unsigned short* Wg = (const unsigned short*)W;

    auto STAGE = [&](int buf, int k0) {   // 6 global_load_lds instructions per wave
        #pragma unroll
        for (int l = 0; l < 2; ++l) {
            const int s = l * 512 + tid;
            const int row = s >> 3;
            const int srcb = ((s & 7) * 16) ^ ((row & 7) << 4);
            gll16(Ag + (size_t)(bm + row) * K + k0 + (srcb >> 1),
                  (unsigned short*)&As[buf][0][0] + (l * 512 + wid * 64) * 8);
        }
        #pragma unroll
        for (int l = 0; l < 4; ++l) {
            const int s = l * 512 + tid;
            const int row = s >> 3;
            const int srcb = ((s & 7) * 16) ^ ((row & 7) << 4);
            gll16(Wg + (size_t)(bn + row) * K + k0 + (srcb >> 1),
                  (unsigned short*)&Ws[buf][0][0] + (l * 512 + wid * 64) * 8);
        }
    };

    const int nt = K >> 6;
    STAGE(0, 0);
    if (nt > 1) STAGE(1, PBK);
    __syncthreads();   // one-time full drain; pipeline starts inside the loop

    int c0 = 0, c1 = 1, c2 = 2;
    for (int t = 0; t < nt; ++t) {
        const char* Ab = (const char*)&As[c0][0][0];
        const char* Bb = (const char*)&Ws[c0][0][0];

        // ---- phase 0: B frags + A m=0; issue stage for t+2 ----
        bf8 bF[4][2];
        #pragma unroll
        for (int n = 0; n < 4; ++n) {
            const int row = wc * 64 + n * 16 + fr;
            #pragma unroll
            for (int kk = 0; kk < 2; ++kk) {
                const int off = (kk * 64 + hi * 16) ^ ((row & 7) << 4);
                bF[n][kk] = *(const bf8*)(Bb + row * 128 + off);
            }
        }
        bf8 a0, a1;
        {
            const int row = wr * 64 + fr;
            a0 = *(const bf8*)(Ab + row * 128 + ((hi * 16)      ^ ((row & 7) << 4)));
            a1 = *(const bf8*)(Ab + row * 128 + ((64 + hi * 16) ^ ((row & 7) << 4)));
        }
        if (t + 2 < nt) STAGE(c2, (t + 2) * PBK);
        __builtin_amdgcn_s_barrier();
        __builtin_amdgcn_s_setprio(1);
        #pragma unroll
        for (int n = 0; n < 4; ++n) {
            acc[0][n] = __builtin_amdgcn_mfma_f32_16x16x32_bf16(a0, bF[n][0], acc[0][n], 0, 0, 0);
            acc[0][n] = __builtin_amdgcn_mfma_f32_16x16x32_bf16(a1, bF[n][1], acc[0][n], 0, 0, 0);
        }
        __builtin_amdgcn_s_setprio(0);
        __builtin_amdgcn_s_barrier();

        // ---- phases 1..3 ----
        #pragma unroll
        for (int m = 1; m < 4; ++m) {
            const int row = wr * 64 + m * 16 + fr;
            bf8 am0 = *(const bf8*)(Ab + row * 128 + ((hi * 16)      ^ ((row & 7) << 4)));
            bf8 am1 = *(const bf8*)(Ab + row * 128 + ((64 + hi * 16) ^ ((row & 7) << 4)));
            __builtin_amdgcn_s_barrier();
            __builtin_amdgcn_s_setprio(1);
            #pragma unroll
            for (int n = 0; n < 4; ++n) {
                acc[m][n] = __builtin_amdgcn_mfma_f32_16x16x32_bf16(am0, bF[n][0], acc[m][n], 0, 0, 0);
                acc[m][n] = __builtin_amdgcn_mfma_f32_16x16x32_bf16(am1, bF[n][1], acc[m][n], 0, 0, 0);
            }
            __builtin_amdgcn_s_setprio(0);
            if (m < 3) __builtin_amdgcn_s_barrier();
        }

        // ---- tile boundary: counted wait (T4) + raw barrier ----
        if (t + 1 < nt) {
            if (t + 2 < nt) { asm volatile("s_waitcnt vmcnt(6)" ::: "memory"); }
            else            { asm volatile("s_waitcnt vmcnt(0)" ::: "memory"); }
            __builtin_amdgcn_s_barrier();
        }
        const int tmp = c0; c0 = c1; c1 = c2; c2 = tmp;
    }

    const int rj = hi * 4;
    #pragma unroll
    for (int m = 0; m < 4; ++m) {
        #pragma unroll
        for (int j = 0; j < 4; ++j) {
            const size_t row = (size_t)(bm + wr * 64 + m * 16 + rj + j);
            #pragma unroll
            for (int n = 0; n < 4; ++n) {
                const size_t col = (size_t)(bn + wc * 64 + n * 16 + fr);
                float v = acc[m][n][j];
                if (EPI == 1) v += ((const float*)Rp)[row * N + col];
                if (EPI == 2) v += b2f(((const unsigned short*)Rp)[row * N + col]);
                if (EPI == 3) {
                    float gv = b2f(((const unsigned short*)Rp)[row * N + col]);
                    v = (gv / (1.0f + __expf(-gv))) * v;
                }
                if (OUTB) ((unsigned short*)Cp)[row * N + col] = f2bf(v);
                else      ((float*)Cp)[row * N + col] = v;
            }
        }
    }
}

// ============================ MFMA flash attention (swapped QK^T, lane-local softmax, mask-hoist) ============================
#define AQB 128
#define AKV 64

__global__ __launch_bounds__(512) void attn_mfma(const __hip_bfloat16* __restrict__ q,
        const __hip_bfloat16* __restrict__ k, const __hip_bfloat16* __restrict__ vt,
        __hip_bfloat16* __restrict__ y)
{
    __shared__ alignas(16) unsigned short Ks[AKV * HDIM];   // 16KB
    __shared__ alignas(16) unsigned short Vs[HDIM * AKV];   // 16KB
    __shared__ alignas(16) unsigned short Ps[AQB * AKV];    // 16KB

    const int qt = (TT / AQB - 1) - blockIdx.x;
    const int h  = blockIdx.y;
    const int b  = blockIdx.z;
    const int g  = h >> 2;
    const int qbase = qt * AQB;

    const int tid  = threadIdx.x;
    const int lane = tid & 63;
    const int wid  = tid >> 6;
    const int fr   = lane & 15;
    const int fk8  = (lane >> 4) * 8;
    const int rj   = (lane >> 4) * 4;

    bf8 qf[4];
    {
        const unsigned short* qp = (const unsigned short*)q +
            (size_t)(b * TT + qbase + wid * 16 + fr) * CC + h * HDIM;
        #pragma unroll
        for (int c = 0; c < 4; ++c)
            qf[c] = *(const bf8*)(qp + c * 32 + fk8);
    }
    const unsigned short* vtb = (const unsigned short*)vt + (size_t)(b * NKV + g) * HDIM * TT;

    f32x4 oacc[8];
    float m_r = -1e30f, l_r = 0.f;
    #pragma unroll
    for (int n = 0; n < 8; ++n) oacc[n] = (f32x4){0.f, 0.f, 0.f, 0.f};

    const float scale = 0.08838834764831845f;
    const int ntiles = qbase / AKV + 2;
    const int kjr = tid >> 3;
    const int kkc = (tid & 7) * 16;
    const int vdr = tid >> 2;
    const int vjc = (tid & 3) * 16;
    const int qg = qbase + wid * 16 + fr;
    const int prow = wid * 16 + fr;

    u16x8 krg[2], vrg[2];
    auto LOADT = [&](int jb) {
        const unsigned short* kp = (const unsigned short*)k +
            ((size_t)(b * TT + jb + kjr) * (NKV * HDIM)) + g * HDIM + kkc;
        const unsigned short* vp = vtb + (size_t)vdr * TT + jb + vjc;
        #pragma unroll
        for (int c = 0; c < 2; ++c) {
            krg[c] = *(const u16x8*)(kp + c * 8);
            vrg[c] = *(const u16x8*)(vp + c * 8);
        }
    };
    auto WRITET = [&]() {
        #pragma unroll
        for (int c = 0; c < 2; ++c) {
            const int byteK = (kjr * 256 + (kkc + c * 8) * 2) ^ ((kjr & 7) << 4);
            *(u16x8*)((char*)Ks + byteK) = krg[c];
            const int byteV = (vdr * 128 + (vjc + c * 8) * 2) ^ ((vdr & 7) << 4);
            *(u16x8*)((char*)Vs + byteV) = vrg[c];
        }
    };

    LOADT(0);

    for (int tile = 0; tile < ntiles; ++tile) {
        __syncthreads();
        WRITET();
        if (tile + 1 < ntiles) LOADT((tile + 1) * AKV);
        __syncthreads();

        f32x4 s[4];
        #pragma unroll
        for (int n = 0; n < 4; ++n) s[n] = (f32x4){0.f, 0.f, 0.f, 0.f};
        __builtin_amdgcn_s_setprio(1);
        #pragma unroll
        for (int c = 0; c < 4; ++c) {
            #pragma unroll
            for (int n = 0; n < 4; ++n) {
                const int j = n * 16 + fr;
                const int byteB = (j * 256 + (c * 32 + fk8) * 2) ^ ((j & 7) << 4);
                bf8 kf = *(const bf8*)((char*)Ks + byteB);
                s[n] = __builtin_amdgcn_mfma_f32_16x16x32_bf16(kf, qf[c], s[n], 0, 0, 0);
            }
        }
        __builtin_amdgcn_s_setprio(0);

        const int jbase = tile * AKV;
        float sv[4][4];
        float tmax = -1e30f;
        if (jbase + AKV - 1 <= qbase) {
            #pragma unroll
            for (int n = 0; n < 4; ++n)
                #pragma unroll
                for (int j = 0; j < 4; ++j) {
                    sv[n][j] = s[n][j] * scale;
                    tmax = fmaxf(tmax, sv[n][j]);
                }
        } else {
            #pragma unroll
            for (int n = 0; n < 4; ++n)
                #pragma unroll
                for (int j = 0; j < 4; ++j) {
                    const int jg = jbase + n * 16 + rj + j;
                    sv[n][j] = (jg <= qg) ? s[n][j] * scale : -1e30f;
                    tmax = fmaxf(tmax, sv[n][j]);
                }
        }
        tmax = fmaxf(tmax, __shfl_xor(tmax, 16));
        tmax = fmaxf(tmax, __shfl_xor(tmax, 32));
        const bool trig = tmax > m_r + 8.0f;
        if (__any(trig)) {
            const float alpha = trig ? __expf(m_r - tmax) : 1.0f;
            if (trig) m_r = tmax;
            l_r *= alpha;
            float aj[4];
            #pragma unroll
            for (int j = 0; j < 4; ++j) aj[j] = __shfl(alpha, rj + j);
            #pragma unroll
            for (int n = 0; n < 8; ++n)
                #pragma unroll
                for (int j = 0; j < 4; ++j) oacc[n][j] *= aj[j];
        }
        float tsum = 0.f;
        #pragma unroll
        for (int n = 0; n < 4; ++n)
            #pragma unroll
            for (int j = 0; j < 4; ++j) {
                const float p = __expf(sv[n][j] - m_r);
                tsum += p;
                const int byteP = (prow * 128 + (n * 16 + rj + j) * 2) ^ ((prow & 7) << 4);
                *(unsigned short*)((char*)Ps + byteP) = f2bf(p);
            }
        tsum += __shfl_xor(tsum, 16);
        tsum += __shfl_xor(tsum, 32);
        l_r += tsum;

        __builtin_amdgcn_s_setprio(1);
        #pragma unroll
        for (int c2 = 0; c2 < 2; ++c2) {
            const int byteA = (prow * 128 + (c2 * 32 + fk8) * 2) ^ ((prow & 7) << 4);
            bf8 pf = *(const bf8*)((char*)Ps + byteA);
            #pragma unroll
            for (int n = 0; n < 8; ++n) {
                const int d = n * 16 + fr;
                const int byteB = (d * 128 + (c2 * 32 + fk8) * 2) ^ ((d & 7) << 4);
                bf8 vf = *(const bf8*)((char*)Vs + byteB);
                oacc[n] = __builtin_amdgcn_mfma_f32_16x16x32_bf16(pf, vf, oacc[n], 0, 0, 0);
            }
        }
        __builtin_amdgcn_s_setprio(0);
    }

    const float rl = 1.0f / l_r;
    #pragma unroll
    for (int jj = 0; jj < 4; ++jj) {
        const float inv = __shfl(rl, rj + jj);
        unsigned short* yrow = (unsigned short*)y +
            ((size_t)(b * TT + qbase + wid * 16 + rj + jj) * CC) + h * HDIM;
        #pragma unroll
        for (int n = 0; n < 8; ++n)
            yrow[n * 16 + fr] = f2bf(oacc[n][jj] * inv);
    }
}

// ============================ launch ============================
extern "C" void kernel_launch(void* const* d_in, const int* in_sizes, int n_in,
                              void* d_out, int out_size, void* d_ws, size_t ws_size,
                              hipStream_t stream)
{
    (void)in_sizes; (void)n_in; (void)out_size; (void)ws_size;
    const float* x     = (const float*)d_in[0];
    const float* fc    = (const float*)d_in[1];
    const float* wq    = (const float*)d_in[2];
    const float* wk    = (const float*)d_in[3];
    const float* wv    = (const float*)d_in[4];
    const float* wo    = (const float*)d_in[5];
    const float* w1    = (const float*)d_in[6];
    const float* w2    = (const float*)d_in[7];
    const float* cproj = (const float*)d_in[8];
    const float* g1    = (const float*)d_in[9];
    const float* g2    = (const float*)d_in[10];
    float* out = (float*)d_out;

    const int ROWS = NB * TT;  // 4096
    unsigned char* wsb = (unsigned char*)d_ws;
    __hip_bfloat16* x2b = (__hip_bfloat16*)(wsb);
    __hip_bfloat16* hb  = (__hip_bfloat16*)(wsb + 16777216u);
    __hip_bfloat16* w1b = (__hip_bfloat16*)(wsb + 33554432u);
    __hip_bfloat16* w2b = (__hip_bfloat16*)(wsb + 56623104u);
    __hip_bfloat16* G1  = (__hip_bfloat16*)(wsb + 79691776u);
    __hip_bfloat16* cpb = w1b;
    // phase A views
    __hip_bfloat16* qb   = (__hip_bfloat16*)(wsb + 33554432u);
    __hip_bfloat16* kb   = (__hip_bfloat16*)(wsb + 50331648u);
    __hip_bfloat16* vtb  = (__hip_bfloat16*)(wsb + 54525952u);
    __hip_bfloat16* yb   = (__hip_bfloat16*)(wsb + 58720256u);
    __hip_bfloat16* wbuf = (__hip_bfloat16*)(wsb + 75497472u);

    // 1. h = rmsnorm(x)*g1
    rms_f32_k<<<ROWS, 256, 0, stream>>>(x, g1, hb);
    // 2. fused qkv projection with RoPE epilogue (2ph)
    cvt3_k<<<3072, 256, 0, stream>>>(wq, wk, wv, wbuf);
    gemm_qkv_db<<<dim3(3072 / GBN, ROWS / GBM), 256, 0, stream>>>(hb, wbuf, fc, qb, kb, vtb, ROWS, CC);
    // 3. attention
    attn_mfma<<<dim3(TT / AQB, NH, NB), 512, 0, stream>>>(qb, kb, vtb, yb);
    // 4. x2 = bf16(x + y @ wo^T)  (4-phase T4)
    cvt_k<<<(CC * CC) / 2048, 256, 0, stream>>>(wo, wbuf);
    gemm_8p<1, 1><<<dim3(CC / PBN, ROWS / PBM), 512, 0, stream>>>(yb, wbuf, x, x2b, ROWS, CC, CC);
    // 5. h2 = rmsnorm(x2)*g2
    rms_bf16_k<<<ROWS, 256, 0, stream>>>(x2b, g2, hb);
    // 6. FFN: G1 = h2@w1^T ; G1 = silu(G1) * (h2@w2^T)  (4-phase T4)
    cvt2_k<<<2 * NFFN, 256, 0, stream>>>(w1, w2, w1b, w2b);
    gemm_8p<0, 1><<<dim3(NFFN / PBN, ROWS / PBM), 512, 0, stream>>>(hb, w1b, nullptr, G1, ROWS, NFFN, CC);
    gemm_8p<3, 1><<<dim3(NFFN / PBN, ROWS / PBM), 512, 0, stream>>>(hb, w2b, G1, G1, ROWS, NFFN, CC);
    // 7. out = x2 + G1 @ cproj^T  (4-phase T4)
    cvt_k<<<(CC * NFFN) / 2048, 256, 0, stream>>>(cproj, cpb);
    gemm_8p<2, 0><<<dim3(CC / PBN, ROWS / PBM), 512, 0, stream>>>(G1, cpb, x2b, out, ROWS, CC, NFFN);
}

// Round 22
// 616.712 us; speedup vs baseline: 1.0161x; 1.0161x over previous
//
#include <hip/hip_runtime.h>
#include <hip/hip_bf16.h>
#include <math.h>

#define TT   2048
#define CC   2048
#define NB   2
#define NH   16
#define NKV  4
#define HDIM 128
#define NFFN 5632

typedef __attribute__((ext_vector_type(8))) short     bf8;
typedef __attribute__((ext_vector_type(4))) float     f32x4;
typedef __attribute__((ext_vector_type(8))) unsigned short u16x8;
typedef __attribute__((ext_vector_type(4))) unsigned short u16x4;

__device__ __forceinline__ float b2f(unsigned short u) {
    union { unsigned u; float f; } v; v.u = ((unsigned)u) << 16; return v.f;
}
__device__ __forceinline__ unsigned short f2bf(float f) {
    union { float f; unsigned u; } v; v.f = f;
    unsigned r = (v.u + 0x7fffu + ((v.u >> 16) & 1u)) >> 16;
    return (unsigned short)r;
}
__device__ __forceinline__ void gll16(const void* g, void* l) {
    __builtin_amdgcn_global_load_lds((const __attribute__((address_space(1))) void*)g,
                                     (__attribute__((address_space(3))) void*)l, 16, 0, 0);
}

// ============================ f32 -> bf16 convert ============================
__global__ __launch_bounds__(256) void cvt_k(const float* __restrict__ in,
        __hip_bfloat16* __restrict__ out)
{
    const size_t i = ((size_t)blockIdx.x * 256 + threadIdx.x) * 8;
    float4 a = *(const float4*)(in + i);
    float4 b = *(const float4*)(in + i + 4);
    u16x8 v;
    v[0] = f2bf(a.x); v[1] = f2bf(a.y); v[2] = f2bf(a.z); v[3] = f2bf(a.w);
    v[4] = f2bf(b.x); v[5] = f2bf(b.y); v[6] = f2bf(b.z); v[7] = f2bf(b.w);
    *(u16x8*)((unsigned short*)out + i) = v;
}

// merged qkv-weight convert
__global__ __launch_bounds__(256) void cvt3_k(const float* __restrict__ wq,
        const float* __restrict__ wk, const float* __restrict__ wv,
        __hip_bfloat16* __restrict__ out)
{
    const int row = blockIdx.x;
    const float* src = (row < 2048) ? (wq + (size_t)row * CC)
                     : (row < 2560) ? (wk + (size_t)(row - 2048) * CC)
                                    : (wv + (size_t)(row - 2560) * CC);
    const int e0 = threadIdx.x * 8;
    float4 a = *(const float4*)(src + e0);
    float4 b = *(const float4*)(src + e0 + 4);
    u16x8 v;
    v[0] = f2bf(a.x); v[1] = f2bf(a.y); v[2] = f2bf(a.z); v[3] = f2bf(a.w);
    v[4] = f2bf(b.x); v[5] = f2bf(b.y); v[6] = f2bf(b.z); v[7] = f2bf(b.w);
    *(u16x8*)((unsigned short*)out + (size_t)row * CC + e0) = v;
}

// merged w1/w2 convert
__global__ __launch_bounds__(256) void cvt2_k(const float* __restrict__ w1,
        const float* __restrict__ w2,
        __hip_bfloat16* __restrict__ o1, __hip_bfloat16* __restrict__ o2)
{
    const int row = blockIdx.x;
    const float* src;
    unsigned short* dst;
    if (row < NFFN) { src = w1 + (size_t)row * CC; dst = (unsigned short*)o1 + (size_t)row * CC; }
    else            { src = w2 + (size_t)(row - NFFN) * CC; dst = (unsigned short*)o2 + (size_t)(row - NFFN) * CC; }
    const int e0 = threadIdx.x * 8;
    float4 a = *(const float4*)(src + e0);
    float4 b = *(const float4*)(src + e0 + 4);
    u16x8 v;
    v[0] = f2bf(a.x); v[1] = f2bf(a.y); v[2] = f2bf(a.z); v[3] = f2bf(a.w);
    v[4] = f2bf(b.x); v[5] = f2bf(b.y); v[6] = f2bf(b.z); v[7] = f2bf(b.w);
    *(u16x8*)(dst + e0) = v;
}

// ============================ RMSNorm ============================
__global__ __launch_bounds__(256) void rms_f32_k(const float* __restrict__ x,
        const float* __restrict__ g, __hip_bfloat16* __restrict__ o)
{
    const size_t row = blockIdx.x;
    const int e0 = threadIdx.x * 8;
    float4 a = *(const float4*)(x + row * CC + e0);
    float4 b = *(const float4*)(x + row * CC + e0 + 4);
    float vals[8] = {a.x, a.y, a.z, a.w, b.x, b.y, b.z, b.w};
    float s = 0.f;
    #pragma unroll
    for (int e = 0; e < 8; ++e) s += vals[e] * vals[e];
    #pragma unroll
    for (int off = 32; off; off >>= 1) s += __shfl_xor(s, off);
    __shared__ float wsum[4];
    if ((threadIdx.x & 63) == 0) wsum[threadIdx.x >> 6] = s;
    __syncthreads();
    float scale = rsqrtf((wsum[0] + wsum[1] + wsum[2] + wsum[3]) * (1.0f / CC) + 1e-5f);
    float4 g0 = *(const float4*)(g + e0);
    float4 g1 = *(const float4*)(g + e0 + 4);
    float gs[8] = {g0.x, g0.y, g0.z, g0.w, g1.x, g1.y, g1.z, g1.w};
    u16x8 ov;
    #pragma unroll
    for (int e = 0; e < 8; ++e) ov[e] = f2bf(vals[e] * scale * gs[e]);
    *(u16x8*)((unsigned short*)o + row * CC + e0) = ov;
}

__global__ __launch_bounds__(256) void rms_bf16_k(const __hip_bfloat16* __restrict__ x,
        const float* __restrict__ g, __hip_bfloat16* __restrict__ o)
{
    const size_t row = blockIdx.x;
    const int e0 = threadIdx.x * 8;
    u16x8 xv = *(const u16x8*)((const unsigned short*)x + row * CC + e0);
    float vals[8];
    #pragma unroll
    for (int e = 0; e < 8; ++e) vals[e] = b2f(xv[e]);
    float s = 0.f;
    #pragma unroll
    for (int e = 0; e < 8; ++e) s += vals[e] * vals[e];
    #pragma unroll
    for (int off = 32; off; off >>= 1) s += __shfl_xor(s, off);
    __shared__ float wsum[4];
    if ((threadIdx.x & 63) == 0) wsum[threadIdx.x >> 6] = s;
    __syncthreads();
    float scale = rsqrtf((wsum[0] + wsum[1] + wsum[2] + wsum[3]) * (1.0f / CC) + 1e-5f);
    float4 g0 = *(const float4*)(g + e0);
    float4 g1 = *(const float4*)(g + e0 + 4);
    float gs[8] = {g0.x, g0.y, g0.z, g0.w, g1.x, g1.y, g1.z, g1.w};
    u16x8 ov;
    #pragma unroll
    for (int e = 0; e < 8; ++e) ov[e] = f2bf(vals[e] * scale * gs[e]);
    *(u16x8*)((unsigned short*)o + row * CC + e0) = ov;
}

// ============================ 128^2 bf16 MFMA GEMM, double-buffered (2ph) ============================
#define GBM 128
#define GBN 128
#define GBK 32

// fused QKV GEMM (N=3072, 2ph) + RoPE epilogue
__global__ __launch_bounds__(256) void gemm_qkv_db(
        const __hip_bfloat16* __restrict__ A,
        const __hip_bfloat16* __restrict__ W,
        const float* __restrict__ fc,
        __hip_bfloat16* __restrict__ qo,
        __hip_bfloat16* __restrict__ ko,
        __hip_bfloat16* __restrict__ vto,
        int M, int K)
{
    __shared__ alignas(16) __hip_bfloat16 As[2][GBM][GBK];
    __shared__ alignas(16) __hip_bfloat16 Ws[2][GBN][GBK];
    const int tid  = threadIdx.x;
    const int lane = tid & 63;
    const int wid  = tid >> 6;
    const int wr = wid >> 1, wc = wid & 1;
    const int nwg = gridDim.x * gridDim.y;
    const int lin = blockIdx.y * gridDim.x + blockIdx.x;
    const int nlin = (lin & 7) * (nwg >> 3) + (lin >> 3);
    const int bxs = nlin % gridDim.x, bys = nlin / gridDim.x;
    const int bm = bys * GBM, bn = bxs * GBN;
    const int l4  = lane >> 2;
    const int lk8 = (lane & 3) * 8;
    const int fr  = lane & 15;
    const int fk  = (lane >> 4) * 8;

    f32x4 acc[4][4];
    #pragma unroll
    for (int m = 0; m < 4; ++m)
        #pragma unroll
        for (int n = 0; n < 4; ++n) acc[m][n] = (f32x4){0.f, 0.f, 0.f, 0.f};

    const __hip_bfloat16* ga0 = A + (size_t)(bm + wid * 32 + l4) * K + lk8;
    const __hip_bfloat16* ga1 = A + (size_t)(bm + wid * 32 + 16 + l4) * K + lk8;
    const __hip_bfloat16* gw0 = W + (size_t)(bn + wid * 32 + l4) * K + lk8;
    const __hip_bfloat16* gw1 = W + (size_t)(bn + wid * 32 + 16 + l4) * K + lk8;

    const int nt = K >> 5;
    gll16(ga0, &As[0][wid * 32][0]);
    gll16(ga1, &As[0][wid * 32 + 16][0]);
    gll16(gw0, &Ws[0][wid * 32][0]);
    gll16(gw1, &Ws[0][wid * 32 + 16][0]);

    #pragma unroll 2
    for (int t = 0; t < nt; ++t) {
        const int cur = t & 1;
        __syncthreads();
        if (t + 1 < nt) {
            const int k1 = (t + 1) << 5;
            const int nx = cur ^ 1;
            gll16(ga0 + k1, &As[nx][wid * 32][0]);
            gll16(ga1 + k1, &As[nx][wid * 32 + 16][0]);
            gll16(gw0 + k1, &Ws[nx][wid * 32][0]);
            gll16(gw1 + k1, &Ws[nx][wid * 32 + 16][0]);
        }
        bf8 af[4];
        #pragma unroll
        for (int m = 0; m < 4; ++m)
            af[m] = *(const bf8*)&As[cur][wr * 64 + m * 16 + fr][fk];
        #pragma unroll
        for (int n = 0; n < 4; ++n) {
            bf8 wf = *(const bf8*)&Ws[cur][wc * 64 + n * 16 + fr][fk];
            #pragma unroll
            for (int m = 0; m < 4; ++m)
                acc[m][n] = __builtin_amdgcn_mfma_f32_16x16x32_bf16(af[m], wf, acc[m][n], 0, 0, 0);
        }
    }

    const int rj = (lane >> 4) * 4;
    #pragma unroll
    for (int m = 0; m < 4; ++m) {
        #pragma unroll
        for (int n = 0; n < 4; ++n) {
            const int col = bn + wc * 64 + n * 16 + fr;
            const int row0 = bm + wr * 64 + m * 16 + rj;
            if (col < 2560) {
                const int i2 = ((col & 127) >> 1) * 2;
                const int role = col & 1;
                #pragma unroll
                for (int j = 0; j < 4; ++j) {
                    const int t0 = (row0 + j) & (TT - 1);
                    const float cv = fc[t0 * HDIM + i2];
                    const float sv = fc[t0 * HDIM + i2 + 1];
                    const float v = acc[m][n][j];
                    const float partner = __shfl_xor(v, 1);
                    const float o = role ? (partner * sv + v * cv) : (v * cv - partner * sv);
                    if (col < 2048)
                        ((unsigned short*)qo)[(size_t)(row0 + j) * CC + col] = f2bf(o);
                    else
                        ((unsigned short*)ko)[(size_t)(row0 + j) * (NKV * HDIM) + (col - 2048)] = f2bf(o);
                }
            } else {
                const int vc = col - 2560;
                const int g = vc >> 7, d = vc & 127;
                const int b = row0 >> 11, t0 = row0 & (TT - 1);
                unsigned short* vp = (unsigned short*)vto +
                    ((size_t)(b * NKV + g) * HDIM + d) * TT + t0;
                u16x4 ov;
                #pragma unroll
                for (int j = 0; j < 4; ++j) ov[j] = f2bf(acc[m][n][j]);
                *(u16x4*)vp = ov;
            }
        }
    }
}

// ============================ 128x256 bf16 MFMA GEMM, 4-phase pipelined (N-major swizzle) ============================
#define PBM 128
#define PBN 256
#define PBK 64

template<int EPI, int OUTB>
__global__ __launch_bounds__(512) void gemm_8p(
        const __hip_bfloat16* __restrict__ A,
        const __hip_bfloat16* __restrict__ W,
        const void* __restrict__ Rp,
        void* __restrict__ Cp,
        int M, int N, int K)
{
    __shared__ alignas(16) __hip_bfloat16 As[2][PBM][PBK];
    __shared__ alignas(16) __hip_bfloat16 Ws[2][PBN][PBK];
    const int tid  = threadIdx.x;
    const int lane = tid & 63;
    const int wid  = tid >> 6;
    const int wr = wid >> 2, wc = wid & 3;
    // N-major linearization: same-W-panel blocks adjacent -> W-panel L2-resident per XCD
    const int nwg = gridDim.x * gridDim.y;
    const int lin = blockIdx.x * gridDim.y + blockIdx.y;
    const int nlin = (lin & 7) * (nwg >> 3) + (lin >> 3);
    const int bys = nlin % gridDim.y, bxs = nlin / gridDim.y;
    const int bm = bys * PBM, bn = bxs * PBN;
    const int fr = lane & 15;
    const int hi = lane >> 4;

    f32x4 acc[4][4];
    #pragma unroll
    for (int m = 0; m < 4; ++m)
        #pragma unroll
        for (int n = 0; n < 4; ++n) acc[m][n] = (f32x4){0.f, 0.f, 0.f, 0.f};

    const unsigned short* Ag = (const unsigned short*)A;
    const unsigned short* Wg = (const unsigned short*)W;

    auto STAGE = [&](int buf, int k0) {
        #pragma unroll
        for (int l = 0; l < 2; ++l) {
            const int s = l * 512 + tid;
            const int row = s >> 3;
            const int srcb = ((s & 7) * 16) ^ ((row & 7) << 4);
            gll16(Ag + (size_t)(bm + row) * K + k0 + (srcb >> 1),
                  (unsigned short*)&As[buf][0][0] + (l * 512 + wid * 64) * 8);
        }
        #pragma unroll
        for (int l = 0; l < 4; ++l) {
            const int s = l * 512 + tid;
            const int row = s >> 3;
            const int srcb = ((s & 7) * 16) ^ ((row & 7) << 4);
            gll16(Wg + (size_t)(bn + row) * K + k0 + (srcb >> 1),
                  (unsigned short*)&Ws[buf][0][0] + (l * 512 + wid * 64) * 8);
        }
    };

    const int nt = K >> 6;
    STAGE(0, 0);
    __syncthreads();

    for (int t = 0; t < nt; ++t) {
        const int cur = t & 1;
        const char* Ab = (const char*)&As[cur][0][0];
        const char* Bb = (const char*)&Ws[cur][0][0];

        bf8 bF[4][2];
        #pragma unroll
        for (int n = 0; n < 4; ++n) {
            const int row = wc * 64 + n * 16 + fr;
            #pragma unroll
            for (int kk = 0; kk < 2; ++kk) {
                const int off = (kk * 64 + hi * 16) ^ ((row & 7) << 4);
                bF[n][kk] = *(const bf8*)(Bb + row * 128 + off);
            }
        }
        bf8 a0, a1;
        {
            const int row = wr * 64 + fr;
            a0 = *(const bf8*)(Ab + row * 128 + ((hi * 16)      ^ ((row & 7) << 4)));
            a1 = *(const bf8*)(Ab + row * 128 + ((64 + hi * 16) ^ ((row & 7) << 4)));
        }
        if (t + 1 < nt) STAGE(cur ^ 1, (t + 1) * PBK);
        __builtin_amdgcn_s_barrier();
        __builtin_amdgcn_s_setprio(1);
        #pragma unroll
        for (int n = 0; n < 4; ++n) {
            acc[0][n] = __builtin_amdgcn_mfma_f32_16x16x32_bf16(a0, bF[n][0], acc[0][n], 0, 0, 0);
            acc[0][n] = __builtin_amdgcn_mfma_f32_16x16x32_bf16(a1, bF[n][1], acc[0][n], 0, 0, 0);
        }
        __builtin_amdgcn_s_setprio(0);
        __builtin_amdgcn_s_barrier();

        #pragma unroll
        for (int m = 1; m < 4; ++m) {
            const int row = wr * 64 + m * 16 + fr;
            bf8 am0 = *(const bf8*)(Ab + row * 128 + ((hi * 16)      ^ ((row & 7) << 4)));
            bf8 am1 = *(const bf8*)(Ab + row * 128 + ((64 + hi * 16) ^ ((row & 7) << 4)));
            __builtin_amdgcn_s_barrier();
            __builtin_amdgcn_s_setprio(1);
            #pragma unroll
            for (int n = 0; n < 4; ++n) {
                acc[m][n] = __builtin_amdgcn_mfma_f32_16x16x32_bf16(am0, bF[n][0], acc[m][n], 0, 0, 0);
                acc[m][n] = __builtin_amdgcn_mfma_f32_16x16x32_bf16(am1, bF[n][1], acc[m][n], 0, 0, 0);
            }
            __builtin_amdgcn_s_setprio(0);
            if (m < 3) __builtin_amdgcn_s_barrier();
        }
        __syncthreads();
    }

    const int rj = hi * 4;
    #pragma unroll
    for (int m = 0; m < 4; ++m) {
        #pragma unroll
        for (int j = 0; j < 4; ++j) {
            const size_t row = (size_t)(bm + wr * 64 + m * 16 + rj + j);
            #pragma unroll
            for (int n = 0; n < 4; ++n) {
                const size_t col = (size_t)(bn + wc * 64 + n * 16 + fr);
                float v = acc[m][n][j];
                if (EPI == 1) v += ((const float*)Rp)[row * N + col];
                if (EPI == 2) v += b2f(((const unsigned short*)Rp)[row * N + col]);
                if (EPI == 3) {
                    float gv = b2f(((const unsigned short*)Rp)[row * N + col]);
                    v = (gv / (1.0f + __expf(-gv))) * v;
                }
                if (OUTB) ((unsigned short*)Cp)[row * N + col] = f2bf(v);
                else      ((float*)Cp)[row * N + col] = v;
            }
        }
    }
}

// ============================ MFMA flash attention (swapped QK^T, lane-local softmax, mask-hoist) ============================
#define AQB 128
#define AKV 64

__global__ __launch_bounds__(512) void attn_mfma(const __hip_bfloat16* __restrict__ q,
        const __hip_bfloat16* __restrict__ k, const __hip_bfloat16* __restrict__ vt,
        __hip_bfloat16* __restrict__ y)
{
    __shared__ alignas(16) unsigned short Ks[AKV * HDIM];   // 16KB
    __shared__ alignas(16) unsigned short Vs[HDIM * AKV];   // 16KB
    __shared__ alignas(16) unsigned short Ps[AQB * AKV];    // 16KB

    const int qt = (TT / AQB - 1) - blockIdx.x;
    const int h  = blockIdx.y;
    const int b  = blockIdx.z;
    const int g  = h >> 2;
    const int qbase = qt * AQB;

    const int tid  = threadIdx.x;
    const int lane = tid & 63;
    const int wid  = tid >> 6;
    const int fr   = lane & 15;
    const int fk8  = (lane >> 4) * 8;
    const int rj   = (lane >> 4) * 4;

    bf8 qf[4];
    {
        const unsigned short* qp = (const unsigned short*)q +
            (size_t)(b * TT + qbase + wid * 16 + fr) * CC + h * HDIM;
        #pragma unroll
        for (int c = 0; c < 4; ++c)
            qf[c] = *(const bf8*)(qp + c * 32 + fk8);
    }
    const unsigned short* vtb = (const unsigned short*)vt + (size_t)(b * NKV + g) * HDIM * TT;

    f32x4 oacc[8];
    float m_r = -1e30f, l_r = 0.f;
    #pragma unroll
    for (int n = 0; n < 8; ++n) oacc[n] = (f32x4){0.f, 0.f, 0.f, 0.f};

    const float scale = 0.08838834764831845f;
    const int ntiles = qbase / AKV + 2;
    const int kjr = tid >> 3;
    const int kkc = (tid & 7) * 16;
    const int vdr = tid >> 2;
    const int vjc = (tid & 3) * 16;
    const int qg = qbase + wid * 16 + fr;
    const int prow = wid * 16 + fr;

    u16x8 krg[2], vrg[2];
    auto LOADT = [&](int jb) {
        const unsigned short* kp = (const unsigned short*)k +
            ((size_t)(b * TT + jb + kjr) * (NKV * HDIM)) + g * HDIM + kkc;
        const unsigned short* vp = vtb + (size_t)vdr * TT + jb + vjc;
        #pragma unroll
        for (int c = 0; c < 2; ++c) {
            krg[c] = *(const u16x8*)(kp + c * 8);
            vrg[c] = *(const u16x8*)(vp + c * 8);
        }
    };
    auto WRITET = [&]() {
        #pragma unroll
        for (int c = 0; c < 2; ++c) {
            const int byteK = (kjr * 256 + (kkc + c * 8) * 2) ^ ((kjr & 7) << 4);
            *(u16x8*)((char*)Ks + byteK) = krg[c];
            const int byteV = (vdr * 128 + (vjc + c * 8) * 2) ^ ((vdr & 7) << 4);
            *(u16x8*)((char*)Vs + byteV) = vrg[c];
        }
    };

    LOADT(0);

    for (int tile = 0; tile < ntiles; ++tile) {
        __syncthreads();
        WRITET();
        if (tile + 1 < ntiles) LOADT((tile + 1) * AKV);
        __syncthreads();

        f32x4 s[4];
        #pragma unroll
        for (int n = 0; n < 4; ++n) s[n] = (f32x4){0.f, 0.f, 0.f, 0.f};
        __builtin_amdgcn_s_setprio(1);
        #pragma unroll
        for (int c = 0; c < 4; ++c) {
            #pragma unroll
            for (int n = 0; n < 4; ++n) {
                const int j = n * 16 + fr;
                const int byteB = (j * 256 + (c * 32 + fk8) * 2) ^ ((j & 7) << 4);
                bf8 kf = *(const bf8*)((char*)Ks + byteB);
                s[n] = __builtin_amdgcn_mfma_f32_16x16x32_bf16(kf, qf[c], s[n], 0, 0, 0);
            }
        }
        __builtin_amdgcn_s_setprio(0);

        const int jbase = tile * AKV;
        float sv[4][4];
        float tmax = -1e30f;
        if (jbase + AKV - 1 <= qbase) {
            #pragma unroll
            for (int n = 0; n < 4; ++n)
                #pragma unroll
                for (int j = 0; j < 4; ++j) {
                    sv[n][j] = s[n][j] * scale;
                    tmax = fmaxf(tmax, sv[n][j]);
                }
        } else {
            #pragma unroll
            for (int n = 0; n < 4; ++n)
                #pragma unroll
                for (int j = 0; j < 4; ++j) {
                    const int jg = jbase + n * 16 + rj + j;
                    sv[n][j] = (jg <= qg) ? s[n][j] * scale : -1e30f;
                    tmax = fmaxf(tmax, sv[n][j]);
                }
        }
        tmax = fmaxf(tmax, __shfl_xor(tmax, 16));
        tmax = fmaxf(tmax, __shfl_xor(tmax, 32));
        const bool trig = tmax > m_r + 8.0f;
        if (__any(trig)) {
            const float alpha = trig ? __expf(m_r - tmax) : 1.0f;
            if (trig) m_r = tmax;
            l_r *= alpha;
            float aj[4];
            #pragma unroll
            for (int j = 0; j < 4; ++j) aj[j] = __shfl(alpha, rj + j);
            #pragma unroll
            for (int n = 0; n < 8; ++n)
                #pragma unroll
                for (int j = 0; j < 4; ++j) oacc[n][j] *= aj[j];
        }
        float tsum = 0.f;
        #pragma unroll
        for (int n = 0; n < 4; ++n)
            #pragma unroll
            for (int j = 0; j < 4; ++j) {
                const float p = __expf(sv[n][j] - m_r);
                tsum += p;
                const int byteP = (prow * 128 + (n * 16 + rj + j) * 2) ^ ((prow & 7) << 4);
                *(unsigned short*)((char*)Ps + byteP) = f2bf(p);
            }
        tsum += __shfl_xor(tsum, 16);
        tsum += __shfl_xor(tsum, 32);
        l_r += tsum;

        __builtin_amdgcn_s_setprio(1);
        #pragma unroll
        for (int c2 = 0; c2 < 2; ++c2) {
            const int byteA = (prow * 128 + (c2 * 32 + fk8) * 2) ^ ((prow & 7) << 4);
            bf8 pf = *(const bf8*)((char*)Ps + byteA);
            #pragma unroll
            for (int n = 0; n < 8; ++n) {
                const int d = n * 16 + fr;
                const int byteB = (d * 128 + (c2 * 32 + fk8) * 2) ^ ((d & 7) << 4);
                bf8 vf = *(const bf8*)((char*)Vs + byteB);
                oacc[n] = __builtin_amdgcn_mfma_f32_16x16x32_bf16(pf, vf, oacc[n], 0, 0, 0);
            }
        }
        __builtin_amdgcn_s_setprio(0);
    }

    const float rl = 1.0f / l_r;
    #pragma unroll
    for (int jj = 0; jj < 4; ++jj) {
        const float inv = __shfl(rl, rj + jj);
        unsigned short* yrow = (unsigned short*)y +
            ((size_t)(b * TT + qbase + wid * 16 + rj + jj) * CC) + h * HDIM;
        #pragma unroll
        for (int n = 0; n < 8; ++n)
            yrow[n * 16 + fr] = f2bf(oacc[n][jj] * inv);
    }
}

// ============================ launch ============================
extern "C" void kernel_launch(void* const* d_in, const int* in_sizes, int n_in,
                              void* d_out, int out_size, void* d_ws, size_t ws_size,
                              hipStream_t stream)
{
    (void)in_sizes; (void)n_in; (void)out_size; (void)ws_size;
    const float* x     = (const float*)d_in[0];
    const float* fc    = (const float*)d_in[1];
    const float* wq    = (const float*)d_in[2];
    const float* wk    = (const float*)d_in[3];
    const float* wv    = (const float*)d_in[4];
    const float* wo    = (const float*)d_in[5];
    const float* w1    = (const float*)d_in[6];
    const float* w2    = (const float*)d_in[7];
    const float* cproj = (const float*)d_in[8];
    const float* g1    = (const float*)d_in[9];
    const float* g2    = (const float*)d_in[10];
    float* out = (float*)d_out;

    const int ROWS = NB * TT;  // 4096
    unsigned char* wsb = (unsigned char*)d_ws;
    __hip_bfloat16* x2b = (__hip_bfloat16*)(wsb);
    __hip_bfloat16* hb  = (__hip_bfloat16*)(wsb + 16777216u);
    __hip_bfloat16* w1b = (__hip_bfloat16*)(wsb + 33554432u);
    __hip_bfloat16* w2b = (__hip_bfloat16*)(wsb + 56623104u);
    __hip_bfloat16* G1  = (__hip_bfloat16*)(wsb + 79691776u);
    __hip_bfloat16* cpb = w1b;
    // phase A views
    __hip_bfloat16* qb   = (__hip_bfloat16*)(wsb + 33554432u);
    __hip_bfloat16* kb   = (__hip_bfloat16*)(wsb + 50331648u);
    __hip_bfloat16* vtb  = (__hip_bfloat16*)(wsb + 54525952u);
    __hip_bfloat16* yb   = (__hip_bfloat16*)(wsb + 58720256u);
    __hip_bfloat16* wbuf = (__hip_bfloat16*)(wsb + 75497472u);

    // 1. h = rmsnorm(x)*g1
    rms_f32_k<<<ROWS, 256, 0, stream>>>(x, g1, hb);
    // 2. fused qkv projection with RoPE epilogue (2ph)
    cvt3_k<<<3072, 256, 0, stream>>>(wq, wk, wv, wbuf);
    gemm_qkv_db<<<dim3(3072 / GBN, ROWS / GBM), 256, 0, stream>>>(hb, wbuf, fc, qb, kb, vtb, ROWS, CC);
    // 3. attention
    attn_mfma<<<dim3(TT / AQB, NH, NB), 512, 0, stream>>>(qb, kb, vtb, yb);
    // 4. x2 = bf16(x + y @ wo^T)  (4-phase)
    cvt_k<<<(CC * CC) / 2048, 256, 0, stream>>>(wo, wbuf);
    gemm_8p<1, 1><<<dim3(CC / PBN, ROWS / PBM), 512, 0, stream>>>(yb, wbuf, x, x2b, ROWS, CC, CC);
    // 5. h2 = rmsnorm(x2)*g2
    rms_bf16_k<<<ROWS, 256, 0, stream>>>(x2b, g2, hb);
    // 6. FFN: G1 = h2@w1^T ; G1 = silu(G1) * (h2@w2^T)  (4-phase)
    cvt2_k<<<2 * NFFN, 256, 0, stream>>>(w1, w2, w1b, w2b);
    gemm_8p<0, 1><<<dim3(NFFN / PBN, ROWS / PBM), 512, 0, stream>>>(hb, w1b, nullptr, G1, ROWS, NFFN, CC);
    gemm_8p<3, 1><<<dim3(NFFN / PBN, ROWS / PBM), 512, 0, stream>>>(hb, w2b, G1, G1, ROWS, NFFN, CC);
    // 7. out = x2 + G1 @ cproj^T  (4-phase)
    cvt_k<<<(CC * NFFN) / 2048, 256, 0, stream>>>(cproj, cpb);
    gemm_8p<2, 0><<<dim3(CC / PBN, ROWS / PBM), 512, 0, stream>>>(G1, cpb, x2b, out, ROWS, CC, NFFN);
}